// Round 2
// baseline (118.901 us; speedup 1.0000x reference)
//
#include <hip/hip_runtime.h>

// Problem constants (from the reference)
#define B_DIM 16384
#define C_DIM 10000
#define C_VEC (C_DIM / 4)       // 2500 float4 per row (40000 B, 16B-aligned rows)
#define A_CONST (-4.0f)

#define NBLK 2048
#define WAVES_PER_BLK 4         // 256 threads / 64
#define NWAVES (NBLK * WAVES_PER_BLK)   // 8192 waves -> exactly 2 rows each

// Combine two online-softmax states (m1,s1),(m2,s2)
__device__ inline void combine(float& m, float& s, float mo, float so) {
    float mn = fmaxf(m, mo);
    s = s * __expf(m - mn) + so * __expf(mo - mn);
    m = mn;
}

// Barrier-free: one 64-lane wave owns each row. No LDS, no __syncthreads.
__global__ __launch_bounds__(256) void ces_rows_kernel(
        const float* __restrict__ x,
        const int* __restrict__ tgt,
        float* __restrict__ partial) {
    const int lane = threadIdx.x & 63;
    const int wid  = blockIdx.x * WAVES_PER_BLK + (threadIdx.x >> 6);

    float acc = 0.0f;
    for (int row = wid; row < B_DIM; row += NWAVES) {
        const float* xr = x + (size_t)row * C_DIM;
        const float4* xv = reinterpret_cast<const float4*>(xr);

        // Online max/sum over this lane's strided slice. 2500 = 39*64 + 4,
        // so every lane runs >= 39 iterations -> m always finite after loop.
        float m = -3.0e38f;     // finite sentinel: exp underflows to 0, no NaN
        float s = 0.0f;
        for (int j = lane; j < C_VEC; j += 64) {
            float4 v = xv[j];
            float m4 = fmaxf(fmaxf(v.x, v.y), fmaxf(v.z, v.w));
            float mn = fmaxf(m, m4);
            s = s * __expf(m - mn)
              + __expf(v.x - mn) + __expf(v.y - mn)
              + __expf(v.z - mn) + __expf(v.w - mn);
            m = mn;
        }

        // 64-lane butterfly: all lanes end with the full-row (m, s)
        #pragma unroll
        for (int off = 32; off >= 1; off >>= 1) {
            combine(m, s, __shfl_xor(m, off), __shfl_xor(s, off));
        }

        const float xt = xr[tgt[row]];           // L2-hot (row just streamed)
        const float neg_logp_t = m + __logf(s) - xt;   // -log_softmax at target
        const float p_t = __expf(xt - m) / s;          // softmax at target
        // a*ce + b*ces per-row contribution (a=b=1, rowsum_p == 1 in fp32):
        acc += (1.0f / B_DIM) * neg_logp_t
             + (A_CONST / B_DIM) * (p_t - 1.0f);
    }
    if (lane == 0) partial[wid] = acc;           // deterministic per-wave slot
}

__global__ __launch_bounds__(1024) void ces_reduce_kernel(
        const float* __restrict__ partial,
        float* __restrict__ out) {
    __shared__ float sm[16];
    const int tid = threadIdx.x;
    float acc = 0.0f;
    #pragma unroll
    for (int k = 0; k < NWAVES / 1024; ++k) acc += partial[tid + k * 1024];
    #pragma unroll
    for (int off = 32; off >= 1; off >>= 1) acc += __shfl_xor(acc, off);
    if ((tid & 63) == 0) sm[tid >> 6] = acc;
    __syncthreads();
    if (tid == 0) {
        float r = 0.0f;
        #pragma unroll
        for (int w = 0; w < 16; ++w) r += sm[w];
        out[0] = r;
    }
}

extern "C" void kernel_launch(void* const* d_in, const int* in_sizes, int n_in,
                              void* d_out, int out_size, void* d_ws, size_t ws_size,
                              hipStream_t stream) {
    const float* outputs = (const float*)d_in[0];   // [B, C] fp32
    const int*   targets = (const int*)d_in[1];     // [B] int
    float* partial = (float*)d_ws;                  // NWAVES floats scratch
    float* out = (float*)d_out;                     // scalar

    ces_rows_kernel<<<NBLK, 256, 0, stream>>>(outputs, targets, partial);
    ces_reduce_kernel<<<1, 1024, 0, stream>>>(partial, out);
}